// Round 1
// baseline (10298.904 us; speedup 1.0000x reference)
//
#include <hip/hip_runtime.h>
#include <cstdint>
#include <cstddef>

// ---------------- problem constants ----------------
#define BB 64
#define LL 196
#define EE 2048
#define AD 512
#define DD 512
#define EM 512
#define VV 10000
#define TTOK 32
#define MT 31
#define KX 3072   /* xfull = [emb 512 | ctx 2048 | h 512] */
#define G4 2048   /* 4*DD */

// ---------------- output offsets (floats) ----------------
#define OUT_PRED 0
#define OUT_CAPS (BB*MT*VV)              /* 19,840,000 */
#define OUT_DL   (OUT_CAPS + BB*TTOK)
#define OUT_ALPH (OUT_DL + BB)
#define OUT_SIDX (OUT_ALPH + BB*MT*LL)

// ---------------- workspace offsets (floats) ----------------
#define OFF_SIDX 0
#define OFF_DL   64
#define OFF_MEAN 128
#define OFF_H    (OFF_MEAN + BB*EE)
#define OFF_C    (OFF_H + BB*DD)
#define OFF_HU   (OFF_C + BB*DD)
#define OFF_XF   (OFF_HU + BB*AD)
#define OFF_EN   (OFF_XF + BB*KX)
#define OFF_P0   (OFF_EN + BB*LL)
#define OFF_P1   (OFF_P0 + BB*G4)
#define OFF_WT   (OFF_P1 + BB*G4)
#define OFF_WAE  (OFF_WT + (size_t)KX*G4)
#define OFF_EBF  (OFF_WAE + (size_t)BB*LL*AD)   /* ushort[BB*LL*EE] lives here */

__device__ inline unsigned short f2bf(float x){
    unsigned u = __float_as_uint(x);
    unsigned r = (u + 0x7FFFu + ((u >> 16) & 1u)) >> 16;
    return (unsigned short)r;
}
__device__ inline float sigm(float x){ return 1.0f/(1.0f + __expf(-x)); }

// ---------------- sort (stable, descending length) ----------------
__global__ void k_sort(const int* __restrict__ lengths, const int* __restrict__ captions,
                       float* __restrict__ out, int* __restrict__ sidx, int* __restrict__ dl){
    __shared__ int len_s[BB];
    __shared__ int pos_s[BB];
    int i = threadIdx.x;
    len_s[i] = lengths[i];
    __syncthreads();
    int li = len_s[i];
    int rank = 0;
    for (int j = 0; j < BB; j++){
        int lj = len_s[j];
        rank += (lj > li) || (lj == li && j < i);
    }
    pos_s[rank] = i;
    __syncthreads();
    int src = pos_s[i];
    sidx[i] = src;
    int d = len_s[src] - 1;
    dl[i] = d;
    out[OUT_SIDX + i] = (float)src;
    out[OUT_DL + i]   = (float)d;
    for (int t = 0; t < TTOK; t++)
        out[OUT_CAPS + i*TTOK + t] = (float)captions[src*TTOK + t];
}

// ---------------- mean over L + bf16 copy of sorted enc ----------------
__global__ void k_meanbf(const float* __restrict__ enc, const int* __restrict__ sidx,
                         float* __restrict__ mean, unsigned short* __restrict__ ebf){
    int b = blockIdx.y;
    int e = blockIdx.x*256 + threadIdx.x;
    int src = sidx[b];
    const float* p = enc + ((size_t)src*LL)*EE + e;
    unsigned short* o = ebf + ((size_t)b*LL)*EE + e;
    float acc = 0.f;
    for (int l = 0; l < LL; l++){
        float v = p[(size_t)l*EE];
        acc += v;
        o[(size_t)l*EE] = f2bf(v);
    }
    mean[b*EE + e] = acc * (1.0f/196.0f);
}

// ---------------- transpose W_ih|W_hh into k-major Wt[3072][2048] ----------------
__global__ void k_wt(const float* __restrict__ W_ih, const float* __restrict__ W_hh,
                     float* __restrict__ Wt){
    __shared__ float tile[32][33];
    int j0 = blockIdx.x*32, k0 = blockIdx.y*32;
    int tx = threadIdx.x, ty = threadIdx.y;
    for (int r = ty; r < 32; r += 8){
        int j = j0 + r, k = k0 + tx;
        float v = (k < 2560) ? W_ih[(size_t)j*2560 + k] : W_hh[(size_t)j*512 + (k - 2560)];
        tile[r][tx] = v;
    }
    __syncthreads();
    for (int r = ty; r < 32; r += 8){
        int k = k0 + r, j = j0 + tx;
        Wt[(size_t)k*G4 + j] = tile[tx][r];
    }
}

// ---------------- h0/c0 = tanh(mean @ ihW/icW + b) ----------------
__global__ void k_h0c0(const float* __restrict__ ih_W, const float* __restrict__ ih_b,
                       const float* __restrict__ ic_W, const float* __restrict__ ic_b,
                       const float* __restrict__ mean, float* __restrict__ h,
                       float* __restrict__ c, float* __restrict__ xf){
    const float* W    = blockIdx.z ? ic_W : ih_W;
    const float* bias = blockIdx.z ? ic_b : ih_b;
    int lane = threadIdx.x & 63, wave = threadIdx.x >> 6;
    int j = blockIdx.x*64 + lane;
    int b0 = blockIdx.y*8 + wave*2;
    const float* x0 = mean + (size_t)b0*EE;
    const float* x1 = x0 + EE;
    float a0 = 0.f, a1 = 0.f;
    for (int k = 0; k < EE; k++){
        float wv = W[(size_t)k*DD + j];
        a0 += wv * x0[k];
        a1 += wv * x1[k];
    }
    float v0 = tanhf(a0 + bias[j]);
    float v1 = tanhf(a1 + bias[j]);
    if (blockIdx.z == 0){
        h[b0*DD + j] = v0; h[(b0+1)*DD + j] = v1;
        xf[b0*KX + 2560 + j] = v0; xf[(b0+1)*KX + 2560 + j] = v1;
    } else {
        c[b0*DD + j] = v0; c[(b0+1)*DD + j] = v1;
    }
}

// ---------------- Wa_enc = enc_sorted @ W_a  (12544x2048 @ 2048x512) ----------------
__global__ void k_waenc(const float* __restrict__ enc, const float* __restrict__ W_a,
                        const int* __restrict__ sidx, float* __restrict__ Wae){
    __shared__ float As[64][17];
    __shared__ float Bs[16][68];
    int tid = threadIdx.x;
    int tx = tid & 15, ty = tid >> 4;
    int brow = blockIdx.y*64, bj = blockIdx.x*64;
    int lrow = tid >> 2;
    int lk4  = (tid & 3)*4;
    int r = brow + lrow;
    int bidx = r / LL, lidx = r % LL;
    const float* arow = enc + ((size_t)sidx[bidx]*LL + lidx)*EE;
    int bjj = tid & 63, bk4 = tid >> 6;
    float acc[4][4] = {};
    for (int k0 = 0; k0 < EE; k0 += 16){
        float4 av = *(const float4*)(arow + k0 + lk4);
        As[lrow][lk4+0] = av.x; As[lrow][lk4+1] = av.y;
        As[lrow][lk4+2] = av.z; As[lrow][lk4+3] = av.w;
        #pragma unroll
        for (int i = 0; i < 4; i++)
            Bs[bk4*4 + i][bjj] = W_a[(size_t)(k0 + bk4*4 + i)*AD + bj + bjj];
        __syncthreads();
        #pragma unroll
        for (int kk = 0; kk < 16; kk++){
            float a0 = As[ty*4+0][kk], a1 = As[ty*4+1][kk];
            float a2 = As[ty*4+2][kk], a3 = As[ty*4+3][kk];
            float4 bv = *(const float4*)(&Bs[kk][tx*4]);
            acc[0][0] += a0*bv.x; acc[0][1] += a0*bv.y; acc[0][2] += a0*bv.z; acc[0][3] += a0*bv.w;
            acc[1][0] += a1*bv.x; acc[1][1] += a1*bv.y; acc[1][2] += a1*bv.z; acc[1][3] += a1*bv.w;
            acc[2][0] += a2*bv.x; acc[2][1] += a2*bv.y; acc[2][2] += a2*bv.z; acc[2][3] += a2*bv.w;
            acc[3][0] += a3*bv.x; acc[3][1] += a3*bv.y; acc[3][2] += a3*bv.z; acc[3][3] += a3*bv.w;
        }
        __syncthreads();
    }
    #pragma unroll
    for (int i = 0; i < 4; i++){
        float4 o = make_float4(acc[i][0], acc[i][1], acc[i][2], acc[i][3]);
        *(float4*)(Wae + (size_t)(brow + ty*4 + i)*AD + bj + tx*4) = o;
    }
}

// ---------------- per-step: energy + emb gather ----------------
__global__ void k_energy(const float* __restrict__ Wae, const float* __restrict__ hU,
                         const float* __restrict__ w_att, const float* __restrict__ emb_table,
                         const int* __restrict__ captions, const int* __restrict__ sidx,
                         float* __restrict__ xf, float* __restrict__ energy, int t){
    int b = blockIdx.y, lc = blockIdx.x;
    int tid = threadIdx.x;
    if (lc == 0){
        int cap = captions[sidx[b]*TTOK + t];
        const float* ep = emb_table + (size_t)cap*EM;
        xf[b*KX + tid]       = ep[tid];
        xf[b*KX + 256 + tid] = ep[256 + tid];
    }
    int lane = tid & 63, wave = tid >> 6;
    const float* hub = hU + (size_t)b*AD;
    int l0 = lc*49;
    for (int l = l0 + wave; l < l0 + 49; l += 4){
        const float* wa = Wae + ((size_t)b*LL + l)*AD;
        float acc = 0.f;
        #pragma unroll
        for (int ii = 0; ii < 8; ii++){
            int a = ii*64 + lane;
            acc += tanhf(wa[a] + hub[a]) * w_att[a];
        }
        #pragma unroll
        for (int off = 32; off; off >>= 1) acc += __shfl_xor(acc, off, 64);
        if (lane == 0) energy[b*LL + l] = acc;
    }
}

// ---------------- per-step: softmax + beta + context (+alpha out) ----------------
__global__ void k_ctx(const unsigned short* __restrict__ ebf, const float* __restrict__ energy,
                      const float* __restrict__ h, const float* __restrict__ fb_W,
                      const float* __restrict__ fb_b, const int* __restrict__ dl,
                      float* __restrict__ xf, float* __restrict__ out, int t){
    __shared__ float red[256];
    __shared__ float alpha_s[LL];
    __shared__ float sbeta;
    int b = blockIdx.y, ec = blockIdx.x, tid = threadIdx.x;

    float e = (tid < LL) ? energy[b*LL + tid] : -3.0e38f;
    red[tid] = e; __syncthreads();
    for (int s = 128; s > 0; s >>= 1){ if (tid < s) red[tid] = fmaxf(red[tid], red[tid+s]); __syncthreads(); }
    float m = red[0]; __syncthreads();

    float p = (tid < LL) ? __expf(e - m) : 0.f;
    red[tid] = p; __syncthreads();
    for (int s = 128; s > 0; s >>= 1){ if (tid < s) red[tid] += red[tid+s]; __syncthreads(); }
    float ssum = red[0]; __syncthreads();
    if (tid < LL) alpha_s[tid] = p / ssum;

    float bv = h[b*DD + tid]*fb_W[tid] + h[b*DD + 256 + tid]*fb_W[256 + tid];
    red[tid] = bv; __syncthreads();
    for (int s = 128; s > 0; s >>= 1){ if (tid < s) red[tid] += red[tid+s]; __syncthreads(); }
    if (tid == 0) sbeta = sigm(red[0] + fb_b[0]);
    __syncthreads();
    float beta = sbeta;

    int e0 = ec*512 + tid*2;
    const unsigned short* pe = ebf + ((size_t)b*LL)*EE + e0;
    float ax = 0.f, ay = 0.f;
    for (int l = 0; l < LL; l++){
        unsigned int u = *(const unsigned int*)(pe + (size_t)l*EE);
        float f0 = __uint_as_float(u << 16);
        float f1 = __uint_as_float(u & 0xFFFF0000u);
        float a = alpha_s[l];
        ax += a*f0; ay += a*f1;
    }
    *(float2*)(xf + (size_t)b*KX + EM + e0) = make_float2(beta*ax, beta*ay);

    if (ec == 0 && tid < LL){
        bool mk = t < dl[b];
        out[OUT_ALPH + ((size_t)b*MT + t)*LL + tid] = mk ? alpha_s[tid] : 0.f;
    }
}

// ---------------- per-step: gates partial GEMM (K-split 2) ----------------
__global__ void k_gates(const float* __restrict__ Wt, const float* __restrict__ xf,
                        float* __restrict__ p0, float* __restrict__ p1){
    __shared__ float xs[256*16];
    int tid = threadIdx.x, lane = tid & 63, wave = tid >> 6;
    int j = blockIdx.x*64 + lane;
    int b0 = blockIdx.y*16;
    int ks = blockIdx.z;
    int wb = wave*4;
    float acc[4] = {0.f,0.f,0.f,0.f};
    for (int kt = 0; kt < 6; kt++){
        int k0 = ks*1536 + kt*256;
        __syncthreads();
        #pragma unroll
        for (int i = 0; i < 16; i++){
            float v = xf[(size_t)(b0 + i)*KX + k0 + tid];
            xs[tid*16 + ((i + (tid & ~3)) & 15)] = v;
        }
        __syncthreads();
        #pragma unroll 4
        for (int kk = 0; kk < 256; kk++){
            const float4 xv = *(const float4*)(xs + kk*16 + ((wb + (kk & ~3)) & 15));
            float wv = Wt[(size_t)(k0 + kk)*G4 + j];
            acc[0] += wv*xv.x; acc[1] += wv*xv.y; acc[2] += wv*xv.z; acc[3] += wv*xv.w;
        }
    }
    float* p = ks ? p1 : p0;
    #pragma unroll
    for (int i = 0; i < 4; i++)
        p[(size_t)(b0 + wb + i)*G4 + j] = acc[i];
}

// ---------------- per-step: LSTM state update ----------------
__global__ void k_update(const float* __restrict__ p0, const float* __restrict__ p1,
                         const float* __restrict__ b_ih, const float* __restrict__ b_hh,
                         const int* __restrict__ dl, float* __restrict__ h,
                         float* __restrict__ c, float* __restrict__ xf, int t){
    int f = blockIdx.x*256 + threadIdx.x;
    int b = f >> 9, d = f & 511;
    int base = b*G4 + d;
    float gi = p0[base]        + p1[base]        + b_ih[d]        + b_hh[d];
    float gf = p0[base+512]    + p1[base+512]    + b_ih[d+512]    + b_hh[d+512];
    float gg = p0[base+1024]   + p1[base+1024]   + b_ih[d+1024]   + b_hh[d+1024];
    float go = p0[base+1536]   + p1[base+1536]   + b_ih[d+1536]   + b_hh[d+1536];
    float ig = sigm(gi), fg = sigm(gf), g = tanhf(gg), o = sigm(go);
    float cold = c[b*DD + d];
    float cn = fg*cold + ig*g;
    float hn = o*tanhf(cn);
    bool mk = t < dl[b];
    float hv = mk ? hn : h[b*DD + d];
    float cv = mk ? cn : cold;
    h[b*DD + d] = hv;
    c[b*DD + d] = cv;
    xf[b*KX + 2560 + d] = hv;
}

// ---------------- per-step: fc prediction + next-step hU ----------------
__global__ void k_pred_hu(const float* __restrict__ fc_W, const float* __restrict__ fc_b,
                          const float* __restrict__ U_a, const float* __restrict__ h,
                          const int* __restrict__ dl, float* __restrict__ out,
                          float* __restrict__ hU, int t, int hu_only){
    __shared__ float xs[128*64];
    int tid = threadIdx.x, lane = tid & 63, wave = tid >> 6;
    int bid = blockIdx.x;
    bool pred; int jc;
    if (hu_only){ pred = false; jc = bid; }
    else if (bid < 157){ pred = true; jc = bid; }
    else { pred = false; jc = bid - 157; }
    const float* W = pred ? fc_W : U_a;
    int N = pred ? VV : AD;
    int j = jc*64 + lane;
    bool jv = j < N;
    int wb = wave*16;
    float acc[16];
    #pragma unroll
    for (int i = 0; i < 16; i++) acc[i] = 0.f;

    int khalf = tid >> 7;       // 0/1
    int kkl   = tid & 127;
    for (int kt = 0; kt < 4; kt++){
        int k0 = kt*128;
        __syncthreads();
        #pragma unroll
        for (int i = 0; i < 32; i++){
            int bbs = i*2 + khalf;
            float v = h[(size_t)bbs*DD + k0 + kkl];
            xs[kkl*64 + ((bbs + (kkl & ~3)) & 63)] = v;
        }
        __syncthreads();
        #pragma unroll 2
        for (int kk = 0; kk < 128; kk++){
            float wv = jv ? W[(size_t)(k0 + kk)*N + j] : 0.f;
            const float* xr = xs + kk*64;
            int s = kk & ~3;
            float4 x0 = *(const float4*)(xr + ((wb + 0  + s) & 63));
            float4 x1 = *(const float4*)(xr + ((wb + 4  + s) & 63));
            float4 x2 = *(const float4*)(xr + ((wb + 8  + s) & 63));
            float4 x3 = *(const float4*)(xr + ((wb + 12 + s) & 63));
            acc[0]  += wv*x0.x; acc[1]  += wv*x0.y; acc[2]  += wv*x0.z; acc[3]  += wv*x0.w;
            acc[4]  += wv*x1.x; acc[5]  += wv*x1.y; acc[6]  += wv*x1.z; acc[7]  += wv*x1.w;
            acc[8]  += wv*x2.x; acc[9]  += wv*x2.y; acc[10] += wv*x2.z; acc[11] += wv*x2.w;
            acc[12] += wv*x3.x; acc[13] += wv*x3.y; acc[14] += wv*x3.z; acc[15] += wv*x3.w;
        }
    }
    if (pred){
        if (jv){
            float bias = fc_b[j];
            #pragma unroll
            for (int i = 0; i < 16; i++){
                int b = wb + i;
                bool mk = t < dl[b];
                out[OUT_PRED + ((size_t)b*MT + t)*VV + j] = mk ? acc[i] + bias : 0.f;
            }
        }
    } else {
        #pragma unroll
        for (int i = 0; i < 16; i++){
            int b = wb + i;
            hU[(size_t)b*AD + j] = acc[i];
        }
    }
}

extern "C" void kernel_launch(void* const* d_in, const int* in_sizes, int n_in,
                              void* d_out, int out_size, void* d_ws, size_t ws_size,
                              hipStream_t stream) {
    const float* enc       = (const float*)d_in[0];
    const int*   captions  = (const int*)d_in[1];
    const int*   lengths   = (const int*)d_in[2];
    const float* emb_table = (const float*)d_in[3];
    const float* W_a       = (const float*)d_in[4];
    const float* U_a       = (const float*)d_in[5];
    const float* w_att     = (const float*)d_in[6];
    const float* fb_W      = (const float*)d_in[7];
    const float* fb_b      = (const float*)d_in[8];
    const float* W_ih      = (const float*)d_in[9];
    const float* W_hh      = (const float*)d_in[10];
    const float* b_ih      = (const float*)d_in[11];
    const float* b_hh      = (const float*)d_in[12];
    const float* fc_W      = (const float*)d_in[13];
    const float* fc_b      = (const float*)d_in[14];
    const float* ih_W      = (const float*)d_in[15];
    const float* ih_b      = (const float*)d_in[16];
    const float* ic_W      = (const float*)d_in[17];
    const float* ic_b      = (const float*)d_in[18];

    float* out = (float*)d_out;
    float* ws  = (float*)d_ws;
    int* sidx = (int*)(ws + OFF_SIDX);
    int* dl   = (int*)(ws + OFF_DL);
    float* mean = ws + OFF_MEAN;
    float* h    = ws + OFF_H;
    float* c    = ws + OFF_C;
    float* hU   = ws + OFF_HU;
    float* xf   = ws + OFF_XF;
    float* energy = ws + OFF_EN;
    float* p0   = ws + OFF_P0;
    float* p1   = ws + OFF_P1;
    float* Wt   = ws + OFF_WT;
    float* Wae  = ws + OFF_WAE;
    unsigned short* ebf = (unsigned short*)(ws + OFF_EBF);

    k_sort<<<1, 64, 0, stream>>>(lengths, captions, out, sidx, dl);
    k_meanbf<<<dim3(8, BB), 256, 0, stream>>>(enc, sidx, mean, ebf);
    k_wt<<<dim3(64, 96), dim3(32, 8), 0, stream>>>(W_ih, W_hh, Wt);
    k_h0c0<<<dim3(8, 8, 2), 256, 0, stream>>>(ih_W, ih_b, ic_W, ic_b, mean, h, c, xf);
    k_waenc<<<dim3(8, 196), 256, 0, stream>>>(enc, W_a, sidx, Wae);
    k_pred_hu<<<8, 256, 0, stream>>>(fc_W, fc_b, U_a, h, dl, out, hU, 0, 1);

    for (int t = 0; t < MT; t++){
        k_energy<<<dim3(4, BB), 256, 0, stream>>>(Wae, hU, w_att, emb_table, captions, sidx, xf, energy, t);
        k_ctx<<<dim3(4, BB), 256, 0, stream>>>(ebf, energy, h, fb_W, fb_b, dl, xf, out, t);
        k_gates<<<dim3(32, 4, 2), 256, 0, stream>>>(Wt, xf, p0, p1);
        k_update<<<128, 256, 0, stream>>>(p0, p1, b_ih, b_hh, dl, h, c, xf, t);
        k_pred_hu<<<165, 256, 0, stream>>>(fc_W, fc_b, U_a, h, dl, out, hU, t, 0);
    }
}

// Round 2
// 3302.821 us; speedup vs baseline: 3.1182x; 3.1182x over previous
//
#include <hip/hip_runtime.h>
#include <cstdint>
#include <cstddef>

// ---------------- problem constants ----------------
#define BB 64
#define LL 196
#define EE 2048
#define AD 512
#define DD 512
#define EM 512
#define VV 10000
#define TTOK 32
#define MT 31
#define KX 3072   /* xfull = [emb 512 | ctx 2048 | h 512] */
#define G4 2048   /* 4*DD */
#define VPAD 10048 /* 157*64 */

// ---------------- output offsets (floats) ----------------
#define OUT_PRED 0
#define OUT_CAPS (BB*MT*VV)
#define OUT_DL   (OUT_CAPS + BB*TTOK)
#define OUT_ALPH (OUT_DL + BB)
#define OUT_SIDX (OUT_ALPH + BB*MT*LL)

// ---------------- workspace offsets (floats, all 64-aligned) ----------------
#define OFF_SIDX 0
#define OFF_DL   64
#define OFF_MEAN 128
#define OFF_C    (OFF_MEAN + BB*EE)            /* 131200 */
#define OFF_HU   (OFF_C + BB*DD)               /* 163968 */
#define OFF_GACC (OFF_HU + BB*DD)              /* 196736 */
#define OFF_HB   (OFF_GACC + BB*G4)            /* 327808 : bf16 hb[64][512] */
#define OFF_XFB  (OFF_HB + BB*DD/2)            /* 344192 : bf16 xfb[64][3072] */
#define OFF_WB   (OFF_XFB + BB*KX/2)           /* 442496 : bf16 Wb[2048][3072] */
#define OFF_FCWB (OFF_WB + (size_t)G4*KX/2)    /* bf16 fcWb[10048][512] */
#define OFF_UAB  (OFF_FCWB + (size_t)VPAD*DD/2)/* bf16 Uab[512][512] */
#define OFF_WAB  (OFF_UAB + (size_t)AD*DD/2)   /* bf16 Wab[512][2048] */
#define OFF_WAEB (OFF_WAB + (size_t)AD*EE/2)   /* bf16 Waeb[12544][512] */
#define OFF_EBF  (OFF_WAEB + (size_t)BB*LL*AD/2) /* bf16 ebf[64][196][2048] */

typedef unsigned short u16;
typedef __attribute__((ext_vector_type(8))) short bf16x8;
typedef __attribute__((ext_vector_type(4))) float f32x4;
#define MFMA16(a,b,c) __builtin_amdgcn_mfma_f32_16x16x32_bf16(a,b,c,0,0,0)

__device__ inline u16 f2bf(float x){
    unsigned u = __float_as_uint(x);
    unsigned r = (u + 0x7FFFu + ((u >> 16) & 1u)) >> 16;
    return (u16)r;
}
__device__ inline float bf2f(u16 x){ return __uint_as_float(((unsigned)x) << 16); }
__device__ inline float sigm(float x){ return 1.0f/(1.0f + __expf(-x)); }
__device__ inline float ftanh(float x){ return 2.0f/(1.0f + __expf(-2.0f*x)) - 1.0f; }

// ---------------- sort (stable, descending length) ----------------
__global__ void k_sort(const int* __restrict__ lengths, const int* __restrict__ captions,
                       float* __restrict__ out, int* __restrict__ sidx, int* __restrict__ dl){
    __shared__ int len_s[BB];
    __shared__ int pos_s[BB];
    int i = threadIdx.x;
    len_s[i] = lengths[i];
    __syncthreads();
    int li = len_s[i];
    int rank = 0;
    for (int j = 0; j < BB; j++){
        int lj = len_s[j];
        rank += (lj > li) || (lj == li && j < i);
    }
    pos_s[rank] = i;
    __syncthreads();
    int src = pos_s[i];
    sidx[i] = src;
    int d = len_s[src] - 1;
    dl[i] = d;
    out[OUT_SIDX + i] = (float)src;
    out[OUT_DL + i]   = (float)d;
    for (int t = 0; t < TTOK; t++)
        out[OUT_CAPS + i*TTOK + t] = (float)captions[src*TTOK + t];
}

// ---------------- mean over L + bf16 copy of sorted enc ----------------
__global__ void k_meanbf(const float* __restrict__ enc, const int* __restrict__ sidx,
                         float* __restrict__ mean, u16* __restrict__ ebf){
    int b = blockIdx.y;
    int e = blockIdx.x*256 + threadIdx.x;
    int src = sidx[b];
    const float* p = enc + ((size_t)src*LL)*EE + e;
    u16* o = ebf + ((size_t)b*LL)*EE + e;
    float acc = 0.f;
    for (int l = 0; l < LL; l++){
        float v = p[(size_t)l*EE];
        acc += v;
        o[(size_t)l*EE] = f2bf(v);
    }
    mean[b*EE + e] = acc * (1.0f/196.0f);
}

// ---------------- Wb[n][k] bf16 from W_ih|W_hh (already n-major) ----------------
__global__ void k_wb(const float* __restrict__ W_ih, const float* __restrict__ W_hh,
                     u16* __restrict__ Wb){
    int n = blockIdx.y;
    int k = blockIdx.x*256 + threadIdx.x;
    float v = (k < 2560) ? W_ih[(size_t)n*2560 + k] : W_hh[(size_t)n*512 + (k - 2560)];
    Wb[(size_t)n*KX + k] = f2bf(v);
}

// ---------------- generic transpose: in[K][N] f32 -> out[Nout][K] bf16 (zero-pad) ----------------
__global__ void k_tr(const float* __restrict__ in, u16* __restrict__ out, int K, int N){
    __shared__ float tile[32][33];
    int k0 = blockIdx.x*32, n0 = blockIdx.y*32;
    int tx = threadIdx.x, ty = threadIdx.y;
    for (int r = ty; r < 32; r += 8){
        int k = k0 + r, n = n0 + tx;
        tile[r][tx] = (n < N) ? in[(size_t)k*N + n] : 0.f;
    }
    __syncthreads();
    for (int r = ty; r < 32; r += 8){
        int n = n0 + r, k = k0 + tx;
        out[(size_t)n*K + k] = f2bf(tile[tx][r]);
    }
}

// ---------------- h0/c0 = tanh(mean @ ihW/icW + b) ----------------
__global__ void k_h0c0(const float* __restrict__ ih_W, const float* __restrict__ ih_b,
                       const float* __restrict__ ic_W, const float* __restrict__ ic_b,
                       const float* __restrict__ mean, u16* __restrict__ hb,
                       float* __restrict__ c, u16* __restrict__ xfb){
    const float* W    = blockIdx.z ? ic_W : ih_W;
    const float* bias = blockIdx.z ? ic_b : ih_b;
    int lane = threadIdx.x & 63, wave = threadIdx.x >> 6;
    int j = blockIdx.x*64 + lane;
    int b0 = blockIdx.y*8 + wave*2;
    const float* x0 = mean + (size_t)b0*EE;
    const float* x1 = x0 + EE;
    float a0 = 0.f, a1 = 0.f;
    for (int k = 0; k < EE; k++){
        float wv = W[(size_t)k*DD + j];
        a0 += wv * x0[k];
        a1 += wv * x1[k];
    }
    float v0 = tanhf(a0 + bias[j]);
    float v1 = tanhf(a1 + bias[j]);
    if (blockIdx.z == 0){
        hb[b0*DD + j] = f2bf(v0); hb[(b0+1)*DD + j] = f2bf(v1);
        xfb[b0*KX + 2560 + j] = f2bf(v0); xfb[(b0+1)*KX + 2560 + j] = f2bf(v1);
    } else {
        c[b0*DD + j] = v0; c[(b0+1)*DD + j] = v1;
    }
}

// ---------------- gacc seed ----------------
__global__ void k_ginit(const float* __restrict__ b_ih, const float* __restrict__ b_hh,
                        float* __restrict__ gacc){
    int gid = blockIdx.x*256 + threadIdx.x;
    int j = gid & (G4-1);
    gacc[gid] = b_ih[j] + b_hh[j];
}

// ---------------- Waeb = ebf @ Wab^T  (MFMA bf16, 12544x512, K=2048) ----------------
__global__ void k_waenc2(const u16* __restrict__ ebf, const u16* __restrict__ Wab,
                         u16* __restrict__ Waeb){
    int tid = threadIdx.x, lane = tid & 63, w = tid >> 6;
    int lane15 = lane & 15, quad = lane >> 4;
    int brow = blockIdx.y*64;
    int n0 = blockIdx.x*64 + w*16;
    const u16* ap = ebf + (size_t)(brow + lane15)*EE + quad*8;
    const u16* bp = Wab + (size_t)(n0 + lane15)*EE + quad*8;
    f32x4 z = {0.f,0.f,0.f,0.f};
    f32x4 acc[4] = {z,z,z,z};
    #pragma unroll 4
    for (int kc = 0; kc < 64; kc++){
        bf16x8 bv = *(const bf16x8*)(bp + kc*32);
        bf16x8 a0 = *(const bf16x8*)(ap + kc*32);
        bf16x8 a1 = *(const bf16x8*)(ap + 16*EE + kc*32);
        bf16x8 a2 = *(const bf16x8*)(ap + 32*EE + kc*32);
        bf16x8 a3 = *(const bf16x8*)(ap + 48*EE + kc*32);
        acc[0] = MFMA16(a0, bv, acc[0]);
        acc[1] = MFMA16(a1, bv, acc[1]);
        acc[2] = MFMA16(a2, bv, acc[2]);
        acc[3] = MFMA16(a3, bv, acc[3]);
    }
    #pragma unroll
    for (int mt = 0; mt < 4; mt++)
        #pragma unroll
        for (int r = 0; r < 4; r++){
            int row = brow + mt*16 + quad*4 + r;
            Waeb[(size_t)row*AD + n0 + lane15] = f2bf(acc[mt][r]);
        }
}

// ---------------- per-step: fused attention (emb, energy, softmax, beta, ctx) ----------------
__global__ void k_attn(const u16* __restrict__ Waeb, const u16* __restrict__ ebf,
                       const float* __restrict__ hU, const u16* __restrict__ hb,
                       const float* __restrict__ w_att, const float* __restrict__ fb_W,
                       const float* __restrict__ fb_b, const float* __restrict__ emb_table,
                       const int* __restrict__ captions, const int* __restrict__ sidx,
                       const int* __restrict__ dl, u16* __restrict__ xfb,
                       float* __restrict__ out, int t){
    __shared__ float red[512];
    __shared__ float en_s[200];
    __shared__ float alpha_s[200];
    __shared__ float sbeta;
    int b = blockIdx.x, tid = threadIdx.x;
    int lane = tid & 63, w = tid >> 6;

    // emb gather -> xfb[b][0:512]
    int cap = captions[sidx[b]*TTOK + t];
    xfb[(size_t)b*KX + tid] = f2bf(emb_table[(size_t)cap*EM + tid]);

    // energy: hoist hU and w_att into registers (constant over l)
    const float* hub = hU + (size_t)b*AD;
    float hw[8], ww[8];
    #pragma unroll
    for (int ii = 0; ii < 8; ii++){
        hw[ii] = hub[ii*64 + lane];
        ww[ii] = w_att[ii*64 + lane];
    }
    for (int l = w; l < LL; l += 8){
        const u16* wa = Waeb + ((size_t)b*LL + l)*AD;
        float acc = 0.f;
        #pragma unroll
        for (int ii = 0; ii < 8; ii++)
            acc += ftanh(bf2f(wa[ii*64 + lane]) + hw[ii]) * ww[ii];
        #pragma unroll
        for (int off = 32; off; off >>= 1) acc += __shfl_xor(acc, off, 64);
        if (lane == 0) en_s[l] = acc;
    }
    __syncthreads();

    // softmax over 196
    red[tid] = (tid < LL) ? en_s[tid] : -3.0e38f;
    __syncthreads();
    for (int s = 256; s > 0; s >>= 1){ if (tid < s) red[tid] = fmaxf(red[tid], red[tid+s]); __syncthreads(); }
    float mx = red[0]; __syncthreads();
    float p = (tid < LL) ? __expf(en_s[tid] - mx) : 0.f;
    red[tid] = p; __syncthreads();
    for (int s = 256; s > 0; s >>= 1){ if (tid < s) red[tid] += red[tid+s]; __syncthreads(); }
    float ssum = red[0]; __syncthreads();
    if (tid < LL) alpha_s[tid] = p / ssum;

    // beta = sigmoid(h . fb_W + fb_b)
    red[tid] = bf2f(hb[b*DD + tid]) * fb_W[tid];
    __syncthreads();
    for (int s = 256; s > 0; s >>= 1){ if (tid < s) red[tid] += red[tid+s]; __syncthreads(); }
    if (tid == 0) sbeta = sigm(red[0] + fb_b[0]);
    __syncthreads();
    float beta = sbeta;

    // alpha output (masked)
    bool mk = t < dl[b];
    if (tid < LL) out[OUT_ALPH + ((size_t)b*MT + t)*LL + tid] = mk ? alpha_s[tid] : 0.f;

    // ctx: x[b][512+e] = beta * sum_l alpha[l]*ebf[b][l][e]
    #pragma unroll
    for (int q = 0; q < 2; q++){
        int e0 = q*1024 + tid*2;
        const u16* pe = ebf + (size_t)b*LL*EE + e0;
        float ax = 0.f, ay = 0.f;
        for (int l = 0; l < LL; l++){
            unsigned u = *(const unsigned*)(pe + (size_t)l*EE);
            float a = alpha_s[l];
            ax += a * __uint_as_float(u << 16);
            ay += a * __uint_as_float(u & 0xFFFF0000u);
        }
        unsigned pk = (unsigned)f2bf(beta*ax) | ((unsigned)f2bf(beta*ay) << 16);
        *(unsigned*)(xfb + (size_t)b*KX + EM + e0) = pk;
    }
}

// ---------------- per-step: gates MFMA (K-split x4, atomic into pre-seeded gacc) ----------------
__global__ void k_gates(const u16* __restrict__ Wb, const u16* __restrict__ xfb,
                        float* __restrict__ gacc){
    int tid = threadIdx.x, lane = tid & 63, w = tid >> 6;
    int lane15 = lane & 15, quad = lane >> 4;
    int n0 = blockIdx.x*64 + w*16;
    int kbase = blockIdx.y*768;
    const u16* bp = Wb + (size_t)(n0 + lane15)*KX + kbase + quad*8;
    const u16* ap = xfb + (size_t)lane15*KX + kbase + quad*8;
    f32x4 z = {0.f,0.f,0.f,0.f};
    f32x4 acc[4] = {z,z,z,z};
    #pragma unroll 4
    for (int kc = 0; kc < 24; kc++){
        bf16x8 bv = *(const bf16x8*)(bp + kc*32);
        bf16x8 a0 = *(const bf16x8*)(ap + kc*32);
        bf16x8 a1 = *(const bf16x8*)(ap + 16*KX + kc*32);
        bf16x8 a2 = *(const bf16x8*)(ap + 32*KX + kc*32);
        bf16x8 a3 = *(const bf16x8*)(ap + 48*KX + kc*32);
        acc[0] = MFMA16(a0, bv, acc[0]);
        acc[1] = MFMA16(a1, bv, acc[1]);
        acc[2] = MFMA16(a2, bv, acc[2]);
        acc[3] = MFMA16(a3, bv, acc[3]);
    }
    #pragma unroll
    for (int mt = 0; mt < 4; mt++)
        #pragma unroll
        for (int r = 0; r < 4; r++){
            int m = mt*16 + quad*4 + r;
            atomicAdd(&gacc[(size_t)m*G4 + n0 + lane15], acc[mt][r]);
        }
}

// ---------------- per-step: LSTM state update (+ reseed gacc with biases) ----------------
__global__ void k_update(float* __restrict__ gacc, const float* __restrict__ b_ih,
                         const float* __restrict__ b_hh, const int* __restrict__ dl,
                         u16* __restrict__ hb, float* __restrict__ c,
                         u16* __restrict__ xfb, int t){
    int gid = blockIdx.x*256 + threadIdx.x;
    int b = gid >> 9, d = gid & 511;
    size_t base = (size_t)b*G4 + d;
    float gi = gacc[base];
    float gf = gacc[base + 512];
    float gg = gacc[base + 1024];
    float go = gacc[base + 1536];
    float ig = sigm(gi), fg = sigm(gf), g = ftanh(gg), o = sigm(go);
    float cold = c[gid];
    float cn = fg*cold + ig*g;
    float hn = o*ftanh(cn);
    if (t < dl[b]){
        c[gid] = cn;
        u16 hv = f2bf(hn);
        hb[gid] = hv;
        xfb[(size_t)b*KX + 2560 + d] = hv;
    }
    // reseed for next step's gates
    gacc[base]        = b_ih[d]        + b_hh[d];
    gacc[base + 512]  = b_ih[d + 512]  + b_hh[d + 512];
    gacc[base + 1024] = b_ih[d + 1024] + b_hh[d + 1024];
    gacc[base + 1536] = b_ih[d + 1536] + b_hh[d + 1536];
}

// ---------------- per-step: fc prediction + next-step hU (MFMA) ----------------
__global__ void k_pred(const u16* __restrict__ fcWb, const float* __restrict__ fc_b,
                       const u16* __restrict__ Uab, const u16* __restrict__ hb,
                       const int* __restrict__ dl, float* __restrict__ out,
                       float* __restrict__ hU, int t, int hu_only){
    int tid = threadIdx.x, lane = tid & 63, w = tid >> 6;
    int lane15 = lane & 15, quad = lane >> 4;
    int bid = blockIdx.x;
    bool pred; int jc;
    if (hu_only){ pred = false; jc = bid; }
    else if (bid < 157){ pred = true; jc = bid; }
    else { pred = false; jc = bid - 157; }
    const u16* W = pred ? fcWb : Uab;
    int n0 = jc*64 + w*16;
    const u16* bp = W + (size_t)(n0 + lane15)*AD + quad*8;
    const u16* ap = hb + (size_t)lane15*AD + quad*8;
    f32x4 z = {0.f,0.f,0.f,0.f};
    f32x4 acc[4] = {z,z,z,z};
    #pragma unroll 4
    for (int kc = 0; kc < 16; kc++){
        bf16x8 bv = *(const bf16x8*)(bp + kc*32);
        bf16x8 a0 = *(const bf16x8*)(ap + kc*32);
        bf16x8 a1 = *(const bf16x8*)(ap + 16*AD + kc*32);
        bf16x8 a2 = *(const bf16x8*)(ap + 32*AD + kc*32);
        bf16x8 a3 = *(const bf16x8*)(ap + 48*AD + kc*32);
        acc[0] = MFMA16(a0, bv, acc[0]);
        acc[1] = MFMA16(a1, bv, acc[1]);
        acc[2] = MFMA16(a2, bv, acc[2]);
        acc[3] = MFMA16(a3, bv, acc[3]);
    }
    if (pred){
        int j = n0 + lane15;
        if (j < VV){
            float bias = fc_b[j];
            #pragma unroll
            for (int mt = 0; mt < 4; mt++)
                #pragma unroll
                for (int r = 0; r < 4; r++){
                    int b = mt*16 + quad*4 + r;
                    bool mk = t < dl[b];
                    out[OUT_PRED + ((size_t)b*MT + t)*VV + j] = mk ? acc[mt][r] + bias : 0.f;
                }
        }
    } else {
        int n = n0 + lane15;
        #pragma unroll
        for (int mt = 0; mt < 4; mt++)
            #pragma unroll
            for (int r = 0; r < 4; r++){
                int b = mt*16 + quad*4 + r;
                hU[(size_t)b*AD + n] = acc[mt][r];
            }
    }
}

extern "C" void kernel_launch(void* const* d_in, const int* in_sizes, int n_in,
                              void* d_out, int out_size, void* d_ws, size_t ws_size,
                              hipStream_t stream) {
    const float* enc       = (const float*)d_in[0];
    const int*   captions  = (const int*)d_in[1];
    const int*   lengths   = (const int*)d_in[2];
    const float* emb_table = (const float*)d_in[3];
    const float* W_a       = (const float*)d_in[4];
    const float* U_a       = (const float*)d_in[5];
    const float* w_att     = (const float*)d_in[6];
    const float* fb_W      = (const float*)d_in[7];
    const float* fb_b      = (const float*)d_in[8];
    const float* W_ih      = (const float*)d_in[9];
    const float* W_hh      = (const float*)d_in[10];
    const float* b_ih      = (const float*)d_in[11];
    const float* b_hh      = (const float*)d_in[12];
    const float* fc_W      = (const float*)d_in[13];
    const float* fc_b      = (const float*)d_in[14];
    const float* ih_W      = (const float*)d_in[15];
    const float* ih_b      = (const float*)d_in[16];
    const float* ic_W      = (const float*)d_in[17];
    const float* ic_b      = (const float*)d_in[18];

    float* out = (float*)d_out;
    float* ws  = (float*)d_ws;
    int* sidx = (int*)(ws + OFF_SIDX);
    int* dl   = (int*)(ws + OFF_DL);
    float* mean = ws + OFF_MEAN;
    float* c    = ws + OFF_C;
    float* hU   = ws + OFF_HU;
    float* gacc = ws + OFF_GACC;
    u16* hb   = (u16*)(ws + OFF_HB);
    u16* xfb  = (u16*)(ws + OFF_XFB);
    u16* Wb   = (u16*)(ws + OFF_WB);
    u16* fcWb = (u16*)(ws + OFF_FCWB);
    u16* Uab  = (u16*)(ws + OFF_UAB);
    u16* Wab  = (u16*)(ws + OFF_WAB);
    u16* Waeb = (u16*)(ws + OFF_WAEB);
    u16* ebf  = (u16*)(ws + OFF_EBF);

    k_sort<<<1, 64, 0, stream>>>(lengths, captions, out, sidx, dl);
    k_meanbf<<<dim3(8, BB), 256, 0, stream>>>(enc, sidx, mean, ebf);
    k_wb<<<dim3(12, G4), 256, 0, stream>>>(W_ih, W_hh, Wb);
    k_tr<<<dim3(16, 314), dim3(32, 8), 0, stream>>>(fc_W, fcWb, 512, VV);      // fcWb[10048][512]
    k_tr<<<dim3(16, 16),  dim3(32, 8), 0, stream>>>(U_a, Uab, 512, 512);       // Uab[512][512]
    k_tr<<<dim3(64, 16),  dim3(32, 8), 0, stream>>>(W_a, Wab, 2048, 512);      // Wab[512][2048]
    k_h0c0<<<dim3(8, 8, 2), 256, 0, stream>>>(ih_W, ih_b, ic_W, ic_b, mean, hb, c, xfb);
    k_waenc2<<<dim3(8, 196), 256, 0, stream>>>(ebf, Wab, Waeb);
    k_ginit<<<512, 256, 0, stream>>>(b_ih, b_hh, gacc);
    k_pred<<<8, 256, 0, stream>>>(fcWb, fc_b, Uab, hb, dl, out, hU, 0, 1);     // initial hU

    for (int t = 0; t < MT; t++){
        k_attn<<<BB, 512, 0, stream>>>(Waeb, ebf, hU, hb, w_att, fb_W, fb_b,
                                       emb_table, captions, sidx, dl, xfb, out, t);
        k_gates<<<dim3(32, 4), 256, 0, stream>>>(Wb, xfb, gacc);
        k_update<<<128, 256, 0, stream>>>(gacc, b_ih, b_hh, dl, hb, c, xfb, t);
        k_pred<<<165, 256, 0, stream>>>(fcWb, fc_b, Uab, hb, dl, out, hU, t, 0);
    }
}

// Round 3
// 3058.081 us; speedup vs baseline: 3.3678x; 1.0800x over previous
//
#include <hip/hip_runtime.h>
#include <cstdint>
#include <cstddef>

// ---------------- problem constants ----------------
#define BB 64
#define LL 196
#define EE 2048
#define AD 512
#define DD 512
#define EM 512
#define VV 10000
#define TTOK 32
#define MT 31
#define KX 3072   /* xfull = [emb 512 | ctx 2048 | h 512] */
#define G4 2048   /* 4*DD */
#define VPAD 10048 /* 157*64 */

// ---------------- output offsets (floats) ----------------
#define OUT_PRED 0
#define OUT_CAPS (BB*MT*VV)
#define OUT_DL   (OUT_CAPS + BB*TTOK)
#define OUT_ALPH (OUT_DL + BB)
#define OUT_SIDX (OUT_ALPH + BB*MT*LL)

// ---------------- workspace offsets (floats, all 64-aligned) ----------------
#define OFF_SIDX 0
#define OFF_DL   64
#define OFF_MEAN 128
#define OFF_C    (OFF_MEAN + BB*EE)
#define OFF_HU   (OFF_C + BB*DD)
#define OFF_ATT  (OFF_HU + BB*AD)              /* attw[64][256]: alpha[196], beta at [196] */
#define OFF_GACC (OFF_ATT + BB*256)
#define OFF_HB   (OFF_GACC + BB*G4)            /* bf16 hb[64][512] */
#define OFF_XFB  (OFF_HB + BB*DD/2)            /* bf16 xfb[64][3072] */
#define OFF_WB   (OFF_XFB + BB*KX/2)           /* bf16 Wb[2048][3072] */
#define OFF_FCWB (OFF_WB + (size_t)G4*KX/2)    /* bf16 fcWb[10048][512] */
#define OFF_UAB  (OFF_FCWB + (size_t)VPAD*DD/2)/* bf16 Uab[512][512] */
#define OFF_WAB  (OFF_UAB + (size_t)AD*DD/2)   /* bf16 Wab[512][2048] */
#define OFF_WAEB (OFF_WAB + (size_t)AD*EE/2)   /* bf16 Waeb[12544][512] */
#define OFF_EBF  (OFF_WAEB + (size_t)BB*LL*AD/2) /* bf16 ebf[64][196][2048] */

typedef unsigned short u16;
typedef __attribute__((ext_vector_type(8))) short bf16x8;
typedef __attribute__((ext_vector_type(4))) float f32x4;
#define MFMA16(a,b,c) __builtin_amdgcn_mfma_f32_16x16x32_bf16(a,b,c,0,0,0)

__device__ inline u16 f2bf(float x){
    unsigned u = __float_as_uint(x);
    unsigned r = (u + 0x7FFFu + ((u >> 16) & 1u)) >> 16;
    return (u16)r;
}
__device__ inline float bf2f(u16 x){ return __uint_as_float(((unsigned)x) << 16); }
__device__ inline float sigm(float x){ return 1.0f/(1.0f + __expf(-x)); }
__device__ inline float ftanh(float x){ return 2.0f/(1.0f + __expf(-2.0f*x)) - 1.0f; }

// ---------------- sort (stable, descending length) ----------------
__global__ void k_sort(const int* __restrict__ lengths, const int* __restrict__ captions,
                       float* __restrict__ out, int* __restrict__ sidx, int* __restrict__ dl){
    __shared__ int len_s[BB];
    __shared__ int pos_s[BB];
    int i = threadIdx.x;
    len_s[i] = lengths[i];
    __syncthreads();
    int li = len_s[i];
    int rank = 0;
    for (int j = 0; j < BB; j++){
        int lj = len_s[j];
        rank += (lj > li) || (lj == li && j < i);
    }
    pos_s[rank] = i;
    __syncthreads();
    int src = pos_s[i];
    sidx[i] = src;
    int d = len_s[src] - 1;
    dl[i] = d;
    out[OUT_SIDX + i] = (float)src;
    out[OUT_DL + i]   = (float)d;
    for (int t = 0; t < TTOK; t++)
        out[OUT_CAPS + i*TTOK + t] = (float)captions[src*TTOK + t];
}

// ---------------- mean over L + bf16 copy of sorted enc (float4) ----------------
__global__ void k_meanbf(const float* __restrict__ enc, const int* __restrict__ sidx,
                         float* __restrict__ mean, u16* __restrict__ ebf){
    int b = blockIdx.y;
    int e = (blockIdx.x*256 + threadIdx.x)*4;
    int src = sidx[b];
    const float* p = enc + (size_t)src*LL*EE + e;
    u16* o = ebf + (size_t)b*LL*EE + e;
    float sx = 0.f, sy = 0.f, sz = 0.f, sw = 0.f;
    for (int l = 0; l < LL; l++){
        float4 v = *(const float4*)(p + (size_t)l*EE);
        sx += v.x; sy += v.y; sz += v.z; sw += v.w;
        unsigned lo = (unsigned)f2bf(v.x) | ((unsigned)f2bf(v.y) << 16);
        unsigned hi = (unsigned)f2bf(v.z) | ((unsigned)f2bf(v.w) << 16);
        uint2 pk; pk.x = lo; pk.y = hi;
        *(uint2*)(o + (size_t)l*EE) = pk;
    }
    float4 m; m.x = sx*(1.0f/196.0f); m.y = sy*(1.0f/196.0f);
    m.z = sz*(1.0f/196.0f); m.w = sw*(1.0f/196.0f);
    *(float4*)(mean + b*EE + e) = m;
}

// ---------------- Wb[n][k] bf16 from W_ih|W_hh (already n-major) ----------------
__global__ void k_wb(const float* __restrict__ W_ih, const float* __restrict__ W_hh,
                     u16* __restrict__ Wb){
    int n = blockIdx.y;
    int k = blockIdx.x*256 + threadIdx.x;
    float v = (k < 2560) ? W_ih[(size_t)n*2560 + k] : W_hh[(size_t)n*512 + (k - 2560)];
    Wb[(size_t)n*KX + k] = f2bf(v);
}

// ---------------- generic transpose: in[K][N] f32 -> out[Nout][K] bf16 (zero-pad) ----------------
__global__ void k_tr(const float* __restrict__ in, u16* __restrict__ out, int K, int N){
    __shared__ float tile[32][33];
    int k0 = blockIdx.x*32, n0 = blockIdx.y*32;
    int tx = threadIdx.x, ty = threadIdx.y;
    for (int r = ty; r < 32; r += 8){
        int k = k0 + r, n = n0 + tx;
        tile[r][tx] = (n < N) ? in[(size_t)k*N + n] : 0.f;
    }
    __syncthreads();
    for (int r = ty; r < 32; r += 8){
        int n = n0 + r, k = k0 + tx;
        out[(size_t)n*K + k] = f2bf(tile[tx][r]);
    }
}

// ---------------- h0/c0 = tanh(mean @ ihW/icW + b) ----------------
__global__ void k_h0c0(const float* __restrict__ ih_W, const float* __restrict__ ih_b,
                       const float* __restrict__ ic_W, const float* __restrict__ ic_b,
                       const float* __restrict__ mean, u16* __restrict__ hb,
                       float* __restrict__ c, u16* __restrict__ xfb){
    const float* W    = blockIdx.z ? ic_W : ih_W;
    const float* bias = blockIdx.z ? ic_b : ih_b;
    int lane = threadIdx.x & 63, wave = threadIdx.x >> 6;
    int j = blockIdx.x*64 + lane;
    int b0 = blockIdx.y*8 + wave*2;
    const float* x0 = mean + (size_t)b0*EE;
    const float* x1 = x0 + EE;
    float a0 = 0.f, a1 = 0.f;
    for (int k = 0; k < EE; k++){
        float wv = W[(size_t)k*DD + j];
        a0 += wv * x0[k];
        a1 += wv * x1[k];
    }
    float v0 = tanhf(a0 + bias[j]);
    float v1 = tanhf(a1 + bias[j]);
    if (blockIdx.z == 0){
        hb[b0*DD + j] = f2bf(v0); hb[(b0+1)*DD + j] = f2bf(v1);
        xfb[b0*KX + 2560 + j] = f2bf(v0); xfb[(b0+1)*KX + 2560 + j] = f2bf(v1);
    } else {
        c[b0*DD + j] = v0; c[(b0+1)*DD + j] = v1;
    }
}

// ---------------- gacc seed ----------------
__global__ void k_ginit(const float* __restrict__ b_ih, const float* __restrict__ b_hh,
                        float* __restrict__ gacc){
    int gid = blockIdx.x*256 + threadIdx.x;
    int j = gid & (G4-1);
    gacc[gid] = b_ih[j] + b_hh[j];
}

// ---------------- Waeb = ebf @ Wab^T (one block per 64-row tile, full N=512) ----------------
__global__ __launch_bounds__(512) void k_waenc2(const u16* __restrict__ ebf,
                                                const u16* __restrict__ Wab,
                                                u16* __restrict__ Waeb){
    int tid = threadIdx.x, lane = tid & 63, wv = tid >> 6;
    int lane15 = lane & 15, quad = lane >> 4;
    int brow = blockIdx.x*64;
    int nw = wv*64;
    const u16* ap = ebf + (size_t)(brow + lane15)*EE + quad*8;
    const u16* bp = Wab + (size_t)(nw + lane15)*EE + quad*8;
    f32x4 z = {0.f,0.f,0.f,0.f};
    f32x4 acc[4][4] = {{z,z,z,z},{z,z,z,z},{z,z,z,z},{z,z,z,z}};
    #pragma unroll 2
    for (int kc = 0; kc < 64; kc++){
        bf16x8 a[4], bb[4];
        #pragma unroll
        for (int mt = 0; mt < 4; mt++) a[mt]  = *(const bf16x8*)(ap + (size_t)mt*16*EE + kc*32);
        #pragma unroll
        for (int nt = 0; nt < 4; nt++) bb[nt] = *(const bf16x8*)(bp + (size_t)nt*16*EE + kc*32);
        #pragma unroll
        for (int mt = 0; mt < 4; mt++)
            #pragma unroll
            for (int nt = 0; nt < 4; nt++)
                acc[mt][nt] = MFMA16(a[mt], bb[nt], acc[mt][nt]);
    }
    #pragma unroll
    for (int mt = 0; mt < 4; mt++)
        #pragma unroll
        for (int nt = 0; nt < 4; nt++)
            #pragma unroll
            for (int r = 0; r < 4; r++){
                int row = brow + mt*16 + quad*4 + r;
                Waeb[(size_t)row*AD + nw + nt*16 + lane15] = f2bf(acc[mt][nt][r]);
            }
}

// ---------------- per-step: emb gather + energy + softmax + beta (writes attw) ----------------
__global__ __launch_bounds__(512) void k_energy(const u16* __restrict__ Waeb,
                       const float* __restrict__ hU, const u16* __restrict__ hb,
                       const float* __restrict__ w_att, const float* __restrict__ fb_W,
                       const float* __restrict__ fb_b, const float* __restrict__ emb_table,
                       const int* __restrict__ captions, const int* __restrict__ sidx,
                       const int* __restrict__ dl, u16* __restrict__ xfb,
                       float* __restrict__ attw, float* __restrict__ out, int t){
    __shared__ float red[512];
    __shared__ float en_s[200];
    int b = blockIdx.x, tid = threadIdx.x;
    int lane = tid & 63, w = tid >> 6;

    int cap = captions[sidx[b]*TTOK + t];
    xfb[(size_t)b*KX + tid] = f2bf(emb_table[(size_t)cap*EM + tid]);

    const float* hub = hU + (size_t)b*AD;
    float hw[8], ww[8];
    #pragma unroll
    for (int ii = 0; ii < 8; ii++){
        hw[ii] = hub[ii*64 + lane];
        ww[ii] = w_att[ii*64 + lane];
    }
    for (int l = w; l < LL; l += 8){
        const u16* wa = Waeb + ((size_t)b*LL + l)*AD;
        float acc = 0.f;
        #pragma unroll
        for (int ii = 0; ii < 8; ii++)
            acc += ftanh(bf2f(wa[ii*64 + lane]) + hw[ii]) * ww[ii];
        #pragma unroll
        for (int off = 32; off; off >>= 1) acc += __shfl_xor(acc, off, 64);
        if (lane == 0) en_s[l] = acc;
    }
    __syncthreads();

    red[tid] = (tid < LL) ? en_s[tid] : -3.0e38f;
    __syncthreads();
    for (int s = 256; s > 0; s >>= 1){ if (tid < s) red[tid] = fmaxf(red[tid], red[tid+s]); __syncthreads(); }
    float mx = red[0]; __syncthreads();
    float p = (tid < LL) ? __expf(en_s[tid] - mx) : 0.f;
    red[tid] = p; __syncthreads();
    for (int s = 256; s > 0; s >>= 1){ if (tid < s) red[tid] += red[tid+s]; __syncthreads(); }
    float ssum = red[0]; __syncthreads();
    float alpha = p / ssum;
    if (tid < LL){
        attw[b*256 + tid] = alpha;
        out[OUT_ALPH + ((size_t)b*MT + t)*LL + tid] = (t < dl[b]) ? alpha : 0.f;
    }

    red[tid] = bf2f(hb[b*DD + tid]) * fb_W[tid];
    __syncthreads();
    for (int s = 256; s > 0; s >>= 1){ if (tid < s) red[tid] += red[tid+s]; __syncthreads(); }
    if (tid == 0) attw[b*256 + 196] = sigm(red[0] + fb_b[0]);
}

// ---------------- per-step: context (grid (4,64) over e-chunks) ----------------
__global__ void k_ctx(const u16* __restrict__ ebf, const float* __restrict__ attw,
                      u16* __restrict__ xfb){
    __shared__ float alpha_s[LL];
    __shared__ float sbeta;
    int b = blockIdx.y, ec = blockIdx.x, tid = threadIdx.x;
    if (tid < LL) alpha_s[tid] = attw[b*256 + tid];
    if (tid == 255) sbeta = attw[b*256 + 196];
    __syncthreads();
    float beta = sbeta;
    int e0 = ec*512 + tid*2;
    const u16* pe = ebf + (size_t)b*LL*EE + e0;
    float ax = 0.f, ay = 0.f;
    for (int l = 0; l < LL; l++){
        unsigned u = *(const unsigned*)(pe + (size_t)l*EE);
        float a = alpha_s[l];
        ax += a * __uint_as_float(u << 16);
        ay += a * __uint_as_float(u & 0xFFFF0000u);
    }
    unsigned pk = (unsigned)f2bf(beta*ax) | ((unsigned)f2bf(beta*ay) << 16);
    *(unsigned*)(xfb + (size_t)b*KX + EM + e0) = pk;
}

// ---------------- per-step: gates MFMA (K-split x4, atomic into pre-seeded gacc) ----------------
__global__ void k_gates(const u16* __restrict__ Wb, const u16* __restrict__ xfb,
                        float* __restrict__ gacc){
    int tid = threadIdx.x, lane = tid & 63, w = tid >> 6;
    int lane15 = lane & 15, quad = lane >> 4;
    int n0 = blockIdx.x*64 + w*16;
    int kbase = blockIdx.y*768;
    const u16* bp = Wb + (size_t)(n0 + lane15)*KX + kbase + quad*8;
    const u16* ap = xfb + (size_t)lane15*KX + kbase + quad*8;
    f32x4 z = {0.f,0.f,0.f,0.f};
    f32x4 acc[4] = {z,z,z,z};
    #pragma unroll 4
    for (int kc = 0; kc < 24; kc++){
        bf16x8 bv = *(const bf16x8*)(bp + kc*32);
        bf16x8 a0 = *(const bf16x8*)(ap + kc*32);
        bf16x8 a1 = *(const bf16x8*)(ap + 16*KX + kc*32);
        bf16x8 a2 = *(const bf16x8*)(ap + 32*KX + kc*32);
        bf16x8 a3 = *(const bf16x8*)(ap + 48*KX + kc*32);
        acc[0] = MFMA16(a0, bv, acc[0]);
        acc[1] = MFMA16(a1, bv, acc[1]);
        acc[2] = MFMA16(a2, bv, acc[2]);
        acc[3] = MFMA16(a3, bv, acc[3]);
    }
    #pragma unroll
    for (int mt = 0; mt < 4; mt++)
        #pragma unroll
        for (int r = 0; r < 4; r++){
            int m = mt*16 + quad*4 + r;
            atomicAdd(&gacc[(size_t)m*G4 + n0 + lane15], acc[mt][r]);
        }
}

// ---------------- per-step: LSTM state update (+ reseed gacc with biases) ----------------
__global__ void k_update(float* __restrict__ gacc, const float* __restrict__ b_ih,
                         const float* __restrict__ b_hh, const int* __restrict__ dl,
                         u16* __restrict__ hb, float* __restrict__ c,
                         u16* __restrict__ xfb, int t){
    int gid = blockIdx.x*256 + threadIdx.x;
    int b = gid >> 9, d = gid & 511;
    size_t base = (size_t)b*G4 + d;
    float gi = gacc[base];
    float gf = gacc[base + 512];
    float gg = gacc[base + 1024];
    float go = gacc[base + 1536];
    float ig = sigm(gi), fg = sigm(gf), g = ftanh(gg), o = sigm(go);
    float cold = c[gid];
    float cn = fg*cold + ig*g;
    float hn = o*ftanh(cn);
    if (t < dl[b]){
        c[gid] = cn;
        u16 hv = f2bf(hn);
        hb[gid] = hv;
        xfb[(size_t)b*KX + 2560 + d] = hv;
    }
    gacc[base]        = b_ih[d]        + b_hh[d];
    gacc[base + 512]  = b_ih[d + 512]  + b_hh[d + 512];
    gacc[base + 1024] = b_ih[d + 1024] + b_hh[d + 1024];
    gacc[base + 1536] = b_ih[d + 1536] + b_hh[d + 1536];
}

// ---------------- per-step: fc prediction + next-step hU (MFMA) ----------------
__global__ void k_pred(const u16* __restrict__ fcWb, const float* __restrict__ fc_b,
                       const u16* __restrict__ Uab, const u16* __restrict__ hb,
                       const int* __restrict__ dl, float* __restrict__ out,
                       float* __restrict__ hU, int t, int hu_only){
    int tid = threadIdx.x, lane = tid & 63, w = tid >> 6;
    int lane15 = lane & 15, quad = lane >> 4;
    int bid = blockIdx.x;
    bool pred; int jc;
    if (hu_only){ pred = false; jc = bid; }
    else if (bid < 157){ pred = true; jc = bid; }
    else { pred = false; jc = bid - 157; }
    const u16* W = pred ? fcWb : Uab;
    int n0 = jc*64 + w*16;
    const u16* bp = W + (size_t)(n0 + lane15)*AD + quad*8;
    const u16* ap = hb + (size_t)lane15*AD + quad*8;
    f32x4 z = {0.f,0.f,0.f,0.f};
    f32x4 acc[4] = {z,z,z,z};
    #pragma unroll 4
    for (int kc = 0; kc < 16; kc++){
        bf16x8 bv = *(const bf16x8*)(bp + kc*32);
        bf16x8 a0 = *(const bf16x8*)(ap + kc*32);
        bf16x8 a1 = *(const bf16x8*)(ap + 16*AD + kc*32);
        bf16x8 a2 = *(const bf16x8*)(ap + 32*AD + kc*32);
        bf16x8 a3 = *(const bf16x8*)(ap + 48*AD + kc*32);
        acc[0] = MFMA16(a0, bv, acc[0]);
        acc[1] = MFMA16(a1, bv, acc[1]);
        acc[2] = MFMA16(a2, bv, acc[2]);
        acc[3] = MFMA16(a3, bv, acc[3]);
    }
    if (pred){
        int j = n0 + lane15;
        if (j < VV){
            float bias = fc_b[j];
            #pragma unroll
            for (int mt = 0; mt < 4; mt++)
                #pragma unroll
                for (int r = 0; r < 4; r++){
                    int b = mt*16 + quad*4 + r;
                    bool mk = t < dl[b];
                    out[OUT_PRED + ((size_t)b*MT + t)*VV + j] = mk ? acc[mt][r] + bias : 0.f;
                }
        }
    } else {
        int n = n0 + lane15;
        #pragma unroll
        for (int mt = 0; mt < 4; mt++)
            #pragma unroll
            for (int r = 0; r < 4; r++){
                int b = mt*16 + quad*4 + r;
                hU[(size_t)b*AD + n] = acc[mt][r];
            }
    }
}

extern "C" void kernel_launch(void* const* d_in, const int* in_sizes, int n_in,
                              void* d_out, int out_size, void* d_ws, size_t ws_size,
                              hipStream_t stream) {
    const float* enc       = (const float*)d_in[0];
    const int*   captions  = (const int*)d_in[1];
    const int*   lengths   = (const int*)d_in[2];
    const float* emb_table = (const float*)d_in[3];
    const float* W_a       = (const float*)d_in[4];
    const float* U_a       = (const float*)d_in[5];
    const float* w_att     = (const float*)d_in[6];
    const float* fb_W      = (const float*)d_in[7];
    const float* fb_b      = (const float*)d_in[8];
    const float* W_ih      = (const float*)d_in[9];
    const float* W_hh      = (const float*)d_in[10];
    const float* b_ih      = (const float*)d_in[11];
    const float* b_hh      = (const float*)d_in[12];
    const float* fc_W      = (const float*)d_in[13];
    const float* fc_b      = (const float*)d_in[14];
    const float* ih_W      = (const float*)d_in[15];
    const float* ih_b      = (const float*)d_in[16];
    const float* ic_W      = (const float*)d_in[17];
    const float* ic_b      = (const float*)d_in[18];

    float* out = (float*)d_out;
    float* ws  = (float*)d_ws;
    int* sidx = (int*)(ws + OFF_SIDX);
    int* dl   = (int*)(ws + OFF_DL);
    float* mean = ws + OFF_MEAN;
    float* c    = ws + OFF_C;
    float* hU   = ws + OFF_HU;
    float* attw = ws + OFF_ATT;
    float* gacc = ws + OFF_GACC;
    u16* hb   = (u16*)(ws + OFF_HB);
    u16* xfb  = (u16*)(ws + OFF_XFB);
    u16* Wb   = (u16*)(ws + OFF_WB);
    u16* fcWb = (u16*)(ws + OFF_FCWB);
    u16* Uab  = (u16*)(ws + OFF_UAB);
    u16* Wab  = (u16*)(ws + OFF_WAB);
    u16* Waeb = (u16*)(ws + OFF_WAEB);
    u16* ebf  = (u16*)(ws + OFF_EBF);

    k_sort<<<1, 64, 0, stream>>>(lengths, captions, out, sidx, dl);
    k_meanbf<<<dim3(2, BB), 256, 0, stream>>>(enc, sidx, mean, ebf);
    k_wb<<<dim3(12, G4), 256, 0, stream>>>(W_ih, W_hh, Wb);
    k_tr<<<dim3(16, 314), dim3(32, 8), 0, stream>>>(fc_W, fcWb, 512, VV);
    k_tr<<<dim3(16, 16),  dim3(32, 8), 0, stream>>>(U_a, Uab, 512, 512);
    k_tr<<<dim3(64, 16),  dim3(32, 8), 0, stream>>>(W_a, Wab, 2048, 512);
    k_h0c0<<<dim3(8, 8, 2), 256, 0, stream>>>(ih_W, ih_b, ic_W, ic_b, mean, hb, c, xfb);
    k_waenc2<<<196, 512, 0, stream>>>(ebf, Wab, Waeb);
    k_ginit<<<512, 256, 0, stream>>>(b_ih, b_hh, gacc);
    k_pred<<<8, 256, 0, stream>>>(fcWb, fc_b, Uab, hb, dl, out, hU, 0, 1);

    for (int t = 0; t < MT; t++){
        k_energy<<<BB, 512, 0, stream>>>(Waeb, hU, hb, w_att, fb_W, fb_b,
                                         emb_table, captions, sidx, dl, xfb, attw, out, t);
        k_ctx<<<dim3(4, BB), 256, 0, stream>>>(ebf, attw, xfb);
        k_gates<<<dim3(32, 4), 256, 0, stream>>>(Wb, xfb, gacc);
        k_update<<<128, 256, 0, stream>>>(gacc, b_ih, b_hh, dl, hb, c, xfb, t);
        k_pred<<<165, 256, 0, stream>>>(fcWb, fc_b, Uab, hb, dl, out, hU, t, 0);
    }
}

// Round 4
// 2990.554 us; speedup vs baseline: 3.4438x; 1.0226x over previous
//
#include <hip/hip_runtime.h>
#include <cstdint>
#include <cstddef>

// ---------------- problem constants ----------------
#define BB 64
#define LL 196
#define EE 2048
#define AD 512
#define DD 512
#define EM 512
#define VV 10000
#define TTOK 32
#define MT 31
#define KX 3072   /* xfull = [emb 512 | ctx 2048 | h 512] */
#define G4 2048   /* 4*DD */
#define VPAD 10048 /* 157*64 */

// ---------------- output offsets (floats) ----------------
#define OUT_PRED 0
#define OUT_CAPS (BB*MT*VV)
#define OUT_DL   (OUT_CAPS + BB*TTOK)
#define OUT_ALPH (OUT_DL + BB)
#define OUT_SIDX (OUT_ALPH + BB*MT*LL)

// ---------------- workspace offsets (floats, all 64-aligned) ----------------
#define OFF_SIDX 0
#define OFF_DL   64
#define OFF_MEAN 128
#define OFF_C    (OFF_MEAN + BB*EE)
#define OFF_HU   (OFF_C + BB*DD)
#define OFF_ATT  (OFF_HU + BB*AD)              /* attw[64][256]: alpha[196], beta at [196] */
#define OFF_GACC (OFF_ATT + BB*256)
#define OFF_HB   (OFF_GACC + BB*G4)            /* bf16 hb[64][512] */
#define OFF_XFB  (OFF_HB + BB*DD/2)            /* bf16 xfb[64][3072] */
#define OFF_WB   (OFF_XFB + BB*KX/2)           /* bf16 Wb[2048][3072] */
#define OFF_FCWB (OFF_WB + (size_t)G4*KX/2)    /* bf16 fcWb[10048][512] */
#define OFF_UAB  (OFF_FCWB + (size_t)VPAD*DD/2)/* bf16 Uab[512][512] */
#define OFF_WAB  (OFF_UAB + (size_t)AD*DD/2)   /* bf16 Wab[512][2048] */
#define OFF_WAEB (OFF_WAB + (size_t)AD*EE/2)   /* bf16 Waeb[12544][512] */
#define OFF_EBF  (OFF_WAEB + (size_t)BB*LL*AD/2) /* bf16 ebf[64][196][2048] */
// setup-only scratch overlaid on Waeb region (dead until k_waenc2 runs):
#define OFF_MEANB OFF_WAEB                       /* bf16 meanb[64][2048] = 65536 floats */
#define OFF_IHB  (OFF_WAEB + 65536)              /* bf16 ihb[512][2048] = 524288 floats */
#define OFF_ICB  (OFF_WAEB + 65536 + 524288)     /* bf16 icb[512][2048] */

typedef unsigned short u16;
typedef __attribute__((ext_vector_type(8))) short bf16x8;
typedef __attribute__((ext_vector_type(4))) float f32x4;
#define MFMA16(a,b,c) __builtin_amdgcn_mfma_f32_16x16x32_bf16(a,b,c,0,0,0)

__device__ inline u16 f2bf(float x){
    unsigned u = __float_as_uint(x);
    unsigned r = (u + 0x7FFFu + ((u >> 16) & 1u)) >> 16;
    return (u16)r;
}
__device__ inline float bf2f(u16 x){ return __uint_as_float(((unsigned)x) << 16); }
__device__ inline float sigm(float x){ return 1.0f/(1.0f + __expf(-x)); }
__device__ inline float ftanh(float x){ return 2.0f/(1.0f + __expf(-2.0f*x)) - 1.0f; }

// ---------------- sort (stable, descending length) ----------------
__global__ void k_sort(const int* __restrict__ lengths, const int* __restrict__ captions,
                       float* __restrict__ out, int* __restrict__ sidx, int* __restrict__ dl){
    __shared__ int len_s[BB];
    __shared__ int pos_s[BB];
    int i = threadIdx.x;
    len_s[i] = lengths[i];
    __syncthreads();
    int li = len_s[i];
    int rank = 0;
    for (int j = 0; j < BB; j++){
        int lj = len_s[j];
        rank += (lj > li) || (lj == li && j < i);
    }
    pos_s[rank] = i;
    __syncthreads();
    int src = pos_s[i];
    sidx[i] = src;
    int d = len_s[src] - 1;
    dl[i] = d;
    out[OUT_SIDX + i] = (float)src;
    out[OUT_DL + i]   = (float)d;
    for (int t = 0; t < TTOK; t++)
        out[OUT_CAPS + i*TTOK + t] = (float)captions[src*TTOK + t];
}

// ---------------- gacc bias seed + mean zero ----------------
__global__ void k_ginit(const float* __restrict__ b_ih, const float* __restrict__ b_hh,
                        float* __restrict__ gacc, float* __restrict__ mean){
    int gid = blockIdx.x*256 + threadIdx.x;
    if (gid < BB*G4){
        int j = gid & (G4-1);
        gacc[gid] = b_ih[j] + b_hh[j];
    } else {
        mean[gid - BB*G4] = 0.f;
    }
}

// ---------------- mean partial (atomic over l-halves) + bf16 copy of sorted enc ----------------
__global__ void k_meanbf(const float* __restrict__ enc, const int* __restrict__ sidx,
                         float* __restrict__ mean, u16* __restrict__ ebf){
    int b = blockIdx.y;
    int e = (blockIdx.x*256 + threadIdx.x)*4;
    int l0 = blockIdx.z*98, l1 = l0 + 98;
    int src = sidx[b];
    const float* p = enc + (size_t)src*LL*EE + e;
    u16* o = ebf + (size_t)b*LL*EE + e;
    float sx = 0.f, sy = 0.f, sz = 0.f, sw = 0.f;
    for (int l = l0; l < l1; l++){
        float4 v = *(const float4*)(p + (size_t)l*EE);
        sx += v.x; sy += v.y; sz += v.z; sw += v.w;
        unsigned lo = (unsigned)f2bf(v.x) | ((unsigned)f2bf(v.y) << 16);
        unsigned hi = (unsigned)f2bf(v.z) | ((unsigned)f2bf(v.w) << 16);
        uint2 pk; pk.x = lo; pk.y = hi;
        *(uint2*)(o + (size_t)l*EE) = pk;
    }
    atomicAdd(&mean[b*EE + e + 0], sx);
    atomicAdd(&mean[b*EE + e + 1], sy);
    atomicAdd(&mean[b*EE + e + 2], sz);
    atomicAdd(&mean[b*EE + e + 3], sw);
}

// ---------------- meanb = bf16(mean/196) ----------------
__global__ void k_meanb(const float* __restrict__ mean, u16* __restrict__ meanb){
    int i = (blockIdx.x*256 + threadIdx.x)*8;
    float4 a = *(const float4*)(mean + i);
    float4 b = *(const float4*)(mean + i + 4);
    const float s = 1.0f/196.0f;
    uint4 pk;
    pk.x = (unsigned)f2bf(a.x*s) | ((unsigned)f2bf(a.y*s) << 16);
    pk.y = (unsigned)f2bf(a.z*s) | ((unsigned)f2bf(a.w*s) << 16);
    pk.z = (unsigned)f2bf(b.x*s) | ((unsigned)f2bf(b.y*s) << 16);
    pk.w = (unsigned)f2bf(b.z*s) | ((unsigned)f2bf(b.w*s) << 16);
    *(uint4*)(meanb + i) = pk;
}

// ---------------- Wb[n][k] bf16 from W_ih|W_hh (already n-major) ----------------
__global__ void k_wb(const float* __restrict__ W_ih, const float* __restrict__ W_hh,
                     u16* __restrict__ Wb){
    int n = blockIdx.y;
    int k = blockIdx.x*256 + threadIdx.x;
    float v = (k < 2560) ? W_ih[(size_t)n*2560 + k] : W_hh[(size_t)n*512 + (k - 2560)];
    Wb[(size_t)n*KX + k] = f2bf(v);
}

// ---------------- generic transpose: in[K][N] f32 -> out[Nout][K] bf16 (zero-pad) ----------------
__global__ void k_tr(const float* __restrict__ in, u16* __restrict__ out, int K, int N){
    __shared__ float tile[32][33];
    int k0 = blockIdx.x*32, n0 = blockIdx.y*32;
    int tx = threadIdx.x, ty = threadIdx.y;
    for (int r = ty; r < 32; r += 8){
        int k = k0 + r, n = n0 + tx;
        tile[r][tx] = (n < N) ? in[(size_t)k*N + n] : 0.f;
    }
    __syncthreads();
    for (int r = ty; r < 32; r += 8){
        int n = n0 + r, k = k0 + tx;
        out[(size_t)n*K + k] = f2bf(tile[tx][r]);
    }
}

// ---------------- h0/c0 via MFMA: tanh(meanb @ ihb/icb^T + bias) ----------------
__global__ void k_h0c0m(const u16* __restrict__ ihb, const u16* __restrict__ icb,
                        const u16* __restrict__ meanb, const float* __restrict__ ih_b,
                        const float* __restrict__ ic_b, u16* __restrict__ hb,
                        float* __restrict__ c, u16* __restrict__ xfb){
    int tid = threadIdx.x, lane = tid & 63, w = tid >> 6;
    int lane15 = lane & 15, quad = lane >> 4;
    int z = blockIdx.y;
    const u16* Wm = z ? icb : ihb;
    const float* bias = z ? ic_b : ih_b;
    int n0 = blockIdx.x*64 + w*16;
    const u16* bp = Wm + (size_t)(n0 + lane15)*EE + quad*8;
    const u16* ap = meanb + (size_t)lane15*EE + quad*8;
    f32x4 zz = {0.f,0.f,0.f,0.f};
    f32x4 acc[4] = {zz,zz,zz,zz};
    #pragma unroll 4
    for (int kc = 0; kc < 64; kc++){
        bf16x8 bv = *(const bf16x8*)(bp + kc*32);
        bf16x8 a0 = *(const bf16x8*)(ap + kc*32);
        bf16x8 a1 = *(const bf16x8*)(ap + 16*EE + kc*32);
        bf16x8 a2 = *(const bf16x8*)(ap + 32*EE + kc*32);
        bf16x8 a3 = *(const bf16x8*)(ap + 48*EE + kc*32);
        acc[0] = MFMA16(a0, bv, acc[0]);
        acc[1] = MFMA16(a1, bv, acc[1]);
        acc[2] = MFMA16(a2, bv, acc[2]);
        acc[3] = MFMA16(a3, bv, acc[3]);
    }
    int j = n0 + lane15;
    float bj = bias[j];
    #pragma unroll
    for (int mt = 0; mt < 4; mt++)
        #pragma unroll
        for (int r = 0; r < 4; r++){
            int m = mt*16 + quad*4 + r;
            float v = tanhf(acc[mt][r] + bj);
            if (z == 0){
                u16 hv = f2bf(v);
                hb[m*DD + j] = hv;
                xfb[(size_t)m*KX + 2560 + j] = hv;
            } else {
                c[m*DD + j] = v;
            }
        }
}

// ---------------- Waeb = ebf @ Wab^T (one block per 64-row tile, full N=512) ----------------
__global__ __launch_bounds__(512) void k_waenc2(const u16* __restrict__ ebf,
                                                const u16* __restrict__ Wab,
                                                u16* __restrict__ Waeb){
    int tid = threadIdx.x, lane = tid & 63, wv = tid >> 6;
    int lane15 = lane & 15, quad = lane >> 4;
    int brow = blockIdx.x*64;
    int nw = wv*64;
    const u16* ap = ebf + (size_t)(brow + lane15)*EE + quad*8;
    const u16* bp = Wab + (size_t)(nw + lane15)*EE + quad*8;
    f32x4 z = {0.f,0.f,0.f,0.f};
    f32x4 acc[4][4] = {{z,z,z,z},{z,z,z,z},{z,z,z,z},{z,z,z,z}};
    #pragma unroll 2
    for (int kc = 0; kc < 64; kc++){
        bf16x8 a[4], bb[4];
        #pragma unroll
        for (int mt = 0; mt < 4; mt++) a[mt]  = *(const bf16x8*)(ap + (size_t)mt*16*EE + kc*32);
        #pragma unroll
        for (int nt = 0; nt < 4; nt++) bb[nt] = *(const bf16x8*)(bp + (size_t)nt*16*EE + kc*32);
        #pragma unroll
        for (int mt = 0; mt < 4; mt++)
            #pragma unroll
            for (int nt = 0; nt < 4; nt++)
                acc[mt][nt] = MFMA16(a[mt], bb[nt], acc[mt][nt]);
    }
    #pragma unroll
    for (int mt = 0; mt < 4; mt++)
        #pragma unroll
        for (int nt = 0; nt < 4; nt++)
            #pragma unroll
            for (int r = 0; r < 4; r++){
                int row = brow + mt*16 + quad*4 + r;
                Waeb[(size_t)row*AD + nw + nt*16 + lane15] = f2bf(acc[mt][nt][r]);
            }
}

// ---------------- per-step: emb gather + energy + softmax + beta (writes attw) ----------------
__global__ __launch_bounds__(512) void k_energy(const u16* __restrict__ Waeb,
                       const float* __restrict__ hU, const u16* __restrict__ hb,
                       const float* __restrict__ w_att, const float* __restrict__ fb_W,
                       const float* __restrict__ fb_b, const float* __restrict__ emb_table,
                       const int* __restrict__ captions, const int* __restrict__ sidx,
                       const int* __restrict__ dl, u16* __restrict__ xfb,
                       float* __restrict__ attw, float* __restrict__ out, int t){
    __shared__ float red[512];
    __shared__ float en_s[200];
    int b = blockIdx.x, tid = threadIdx.x;
    int lane = tid & 63, w = tid >> 6;

    int cap = captions[sidx[b]*TTOK + t];
    xfb[(size_t)b*KX + tid] = f2bf(emb_table[(size_t)cap*EM + tid]);

    const float* hub = hU + (size_t)b*AD;
    float hw[8], ww[8];
    #pragma unroll
    for (int ii = 0; ii < 8; ii++){
        hw[ii] = hub[ii*64 + lane];
        ww[ii] = w_att[ii*64 + lane];
    }
    for (int l = w; l < LL; l += 8){
        const u16* wa = Waeb + ((size_t)b*LL + l)*AD;
        float acc = 0.f;
        #pragma unroll
        for (int ii = 0; ii < 8; ii++)
            acc += ftanh(bf2f(wa[ii*64 + lane]) + hw[ii]) * ww[ii];
        #pragma unroll
        for (int off = 32; off; off >>= 1) acc += __shfl_xor(acc, off, 64);
        if (lane == 0) en_s[l] = acc;
    }
    __syncthreads();

    red[tid] = (tid < LL) ? en_s[tid] : -3.0e38f;
    __syncthreads();
    for (int s = 256; s > 0; s >>= 1){ if (tid < s) red[tid] = fmaxf(red[tid], red[tid+s]); __syncthreads(); }
    float mx = red[0]; __syncthreads();
    float p = (tid < LL) ? __expf(en_s[tid] - mx) : 0.f;
    red[tid] = p; __syncthreads();
    for (int s = 256; s > 0; s >>= 1){ if (tid < s) red[tid] += red[tid+s]; __syncthreads(); }
    float ssum = red[0]; __syncthreads();
    float alpha = p / ssum;
    if (tid < LL){
        attw[b*256 + tid] = alpha;
        out[OUT_ALPH + ((size_t)b*MT + t)*LL + tid] = (t < dl[b]) ? alpha : 0.f;
    }

    red[tid] = bf2f(hb[b*DD + tid]) * fb_W[tid];
    __syncthreads();
    for (int s = 256; s > 0; s >>= 1){ if (tid < s) red[tid] += red[tid+s]; __syncthreads(); }
    if (tid == 0) attw[b*256 + 196] = sigm(red[0] + fb_b[0]);
}

// ---------------- per-step: context (grid (4,64) over e-chunks) ----------------
__global__ void k_ctx(const u16* __restrict__ ebf, const float* __restrict__ attw,
                      u16* __restrict__ xfb){
    __shared__ float alpha_s[LL];
    __shared__ float sbeta;
    int b = blockIdx.y, ec = blockIdx.x, tid = threadIdx.x;
    if (tid < LL) alpha_s[tid] = attw[b*256 + tid];
    if (tid == 255) sbeta = attw[b*256 + 196];
    __syncthreads();
    float beta = sbeta;
    int e0 = ec*512 + tid*2;
    const u16* pe = ebf + (size_t)b*LL*EE + e0;
    float ax = 0.f, ay = 0.f;
    for (int l = 0; l < LL; l++){
        unsigned u = *(const unsigned*)(pe + (size_t)l*EE);
        float a = alpha_s[l];
        ax += a * __uint_as_float(u << 16);
        ay += a * __uint_as_float(u & 0xFFFF0000u);
    }
    unsigned pk = (unsigned)f2bf(beta*ax) | ((unsigned)f2bf(beta*ay) << 16);
    *(unsigned*)(xfb + (size_t)b*KX + EM + e0) = pk;
}

// ---------------- per-step: gates MFMA (K-split x4, atomic into pre-seeded gacc) ----------------
__global__ void k_gates(const u16* __restrict__ Wb, const u16* __restrict__ xfb,
                        float* __restrict__ gacc){
    int tid = threadIdx.x, lane = tid & 63, w = tid >> 6;
    int lane15 = lane & 15, quad = lane >> 4;
    int n0 = blockIdx.x*64 + w*16;
    int kbase = blockIdx.y*768;
    const u16* bp = Wb + (size_t)(n0 + lane15)*KX + kbase + quad*8;
    const u16* ap = xfb + (size_t)lane15*KX + kbase + quad*8;
    f32x4 z = {0.f,0.f,0.f,0.f};
    f32x4 acc[4] = {z,z,z,z};
    #pragma unroll 4
    for (int kc = 0; kc < 24; kc++){
        bf16x8 bv = *(const bf16x8*)(bp + kc*32);
        bf16x8 a0 = *(const bf16x8*)(ap + kc*32);
        bf16x8 a1 = *(const bf16x8*)(ap + 16*KX + kc*32);
        bf16x8 a2 = *(const bf16x8*)(ap + 32*KX + kc*32);
        bf16x8 a3 = *(const bf16x8*)(ap + 48*KX + kc*32);
        acc[0] = MFMA16(a0, bv, acc[0]);
        acc[1] = MFMA16(a1, bv, acc[1]);
        acc[2] = MFMA16(a2, bv, acc[2]);
        acc[3] = MFMA16(a3, bv, acc[3]);
    }
    #pragma unroll
    for (int mt = 0; mt < 4; mt++)
        #pragma unroll
        for (int r = 0; r < 4; r++){
            int m = mt*16 + quad*4 + r;
            atomicAdd(&gacc[(size_t)m*G4 + n0 + lane15], acc[mt][r]);
        }
}

// ---------------- per-step: LSTM state update (+ reseed gacc with biases) ----------------
__global__ void k_update(float* __restrict__ gacc, const float* __restrict__ b_ih,
                         const float* __restrict__ b_hh, const int* __restrict__ dl,
                         u16* __restrict__ hb, float* __restrict__ c,
                         u16* __restrict__ xfb, int t){
    int gid = blockIdx.x*256 + threadIdx.x;
    int b = gid >> 9, d = gid & 511;
    size_t base = (size_t)b*G4 + d;
    float gi = gacc[base];
    float gf = gacc[base + 512];
    float gg = gacc[base + 1024];
    float go = gacc[base + 1536];
    float ig = sigm(gi), fg = sigm(gf), g = ftanh(gg), o = sigm(go);
    float cold = c[gid];
    float cn = fg*cold + ig*g;
    float hn = o*ftanh(cn);
    if (t < dl[b]){
        c[gid] = cn;
        u16 hv = f2bf(hn);
        hb[gid] = hv;
        xfb[(size_t)b*KX + 2560 + d] = hv;
    }
    gacc[base]        = b_ih[d]        + b_hh[d];
    gacc[base + 512]  = b_ih[d + 512]  + b_hh[d + 512];
    gacc[base + 1024] = b_ih[d + 1024] + b_hh[d + 1024];
    gacc[base + 1536] = b_ih[d + 1536] + b_hh[d + 1536];
}

// ---------------- per-step: fc prediction + next-step hU (MFMA) ----------------
__global__ void k_pred(const u16* __restrict__ fcWb, const float* __restrict__ fc_b,
                       const u16* __restrict__ Uab, const u16* __restrict__ hb,
                       const int* __restrict__ dl, float* __restrict__ out,
                       float* __restrict__ hU, int t, int hu_only){
    int tid = threadIdx.x, lane = tid & 63, w = tid >> 6;
    int lane15 = lane & 15, quad = lane >> 4;
    int bid = blockIdx.x;
    bool pred; int jc;
    if (hu_only){ pred = false; jc = bid; }
    else if (bid < 157){ pred = true; jc = bid; }
    else { pred = false; jc = bid - 157; }
    const u16* W = pred ? fcWb : Uab;
    int n0 = jc*64 + w*16;
    const u16* bp = W + (size_t)(n0 + lane15)*AD + quad*8;
    const u16* ap = hb + (size_t)lane15*AD + quad*8;
    f32x4 z = {0.f,0.f,0.f,0.f};
    f32x4 acc[4] = {z,z,z,z};
    #pragma unroll 4
    for (int kc = 0; kc < 16; kc++){
        bf16x8 bv = *(const bf16x8*)(bp + kc*32);
        bf16x8 a0 = *(const bf16x8*)(ap + kc*32);
        bf16x8 a1 = *(const bf16x8*)(ap + 16*AD + kc*32);
        bf16x8 a2 = *(const bf16x8*)(ap + 32*AD + kc*32);
        bf16x8 a3 = *(const bf16x8*)(ap + 48*AD + kc*32);
        acc[0] = MFMA16(a0, bv, acc[0]);
        acc[1] = MFMA16(a1, bv, acc[1]);
        acc[2] = MFMA16(a2, bv, acc[2]);
        acc[3] = MFMA16(a3, bv, acc[3]);
    }
    if (pred){
        int j = n0 + lane15;
        if (j < VV){
            float bias = fc_b[j];
            #pragma unroll
            for (int mt = 0; mt < 4; mt++)
                #pragma unroll
                for (int r = 0; r < 4; r++){
                    int b = mt*16 + quad*4 + r;
                    bool mk = t < dl[b];
                    out[OUT_PRED + ((size_t)b*MT + t)*VV + j] = mk ? acc[mt][r] + bias : 0.f;
                }
        }
    } else {
        int n = n0 + lane15;
        #pragma unroll
        for (int mt = 0; mt < 4; mt++)
            #pragma unroll
            for (int r = 0; r < 4; r++){
                int b = mt*16 + quad*4 + r;
                hU[(size_t)b*AD + n] = acc[mt][r];
            }
    }
}

extern "C" void kernel_launch(void* const* d_in, const int* in_sizes, int n_in,
                              void* d_out, int out_size, void* d_ws, size_t ws_size,
                              hipStream_t stream) {
    const float* enc       = (const float*)d_in[0];
    const int*   captions  = (const int*)d_in[1];
    const int*   lengths   = (const int*)d_in[2];
    const float* emb_table = (const float*)d_in[3];
    const float* W_a       = (const float*)d_in[4];
    const float* U_a       = (const float*)d_in[5];
    const float* w_att     = (const float*)d_in[6];
    const float* fb_W      = (const float*)d_in[7];
    const float* fb_b      = (const float*)d_in[8];
    const float* W_ih      = (const float*)d_in[9];
    const float* W_hh      = (const float*)d_in[10];
    const float* b_ih      = (const float*)d_in[11];
    const float* b_hh      = (const float*)d_in[12];
    const float* fc_W      = (const float*)d_in[13];
    const float* fc_b      = (const float*)d_in[14];
    const float* ih_W      = (const float*)d_in[15];
    const float* ih_b      = (const float*)d_in[16];
    const float* ic_W      = (const float*)d_in[17];
    const float* ic_b      = (const float*)d_in[18];

    float* out = (float*)d_out;
    float* ws  = (float*)d_ws;
    int* sidx = (int*)(ws + OFF_SIDX);
    int* dl   = (int*)(ws + OFF_DL);
    float* mean = ws + OFF_MEAN;
    float* c    = ws + OFF_C;
    float* hU   = ws + OFF_HU;
    float* attw = ws + OFF_ATT;
    float* gacc = ws + OFF_GACC;
    u16* hb   = (u16*)(ws + OFF_HB);
    u16* xfb  = (u16*)(ws + OFF_XFB);
    u16* Wb   = (u16*)(ws + OFF_WB);
    u16* fcWb = (u16*)(ws + OFF_FCWB);
    u16* Uab  = (u16*)(ws + OFF_UAB);
    u16* Wab  = (u16*)(ws + OFF_WAB);
    u16* Waeb = (u16*)(ws + OFF_WAEB);
    u16* ebf  = (u16*)(ws + OFF_EBF);
    u16* meanb = (u16*)(ws + OFF_MEANB);
    u16* ihb  = (u16*)(ws + OFF_IHB);
    u16* icb  = (u16*)(ws + OFF_ICB);

    k_sort<<<1, 64, 0, stream>>>(lengths, captions, out, sidx, dl);
    k_ginit<<<1024, 256, 0, stream>>>(b_ih, b_hh, gacc, mean);
    k_meanbf<<<dim3(2, BB, 2), 256, 0, stream>>>(enc, sidx, mean, ebf);
    k_meanb<<<64, 256, 0, stream>>>(mean, meanb);
    k_tr<<<dim3(64, 16), dim3(32, 8), 0, stream>>>(ih_W, ihb, 2048, 512);
    k_tr<<<dim3(64, 16), dim3(32, 8), 0, stream>>>(ic_W, icb, 2048, 512);
    k_h0c0m<<<dim3(8, 2), 256, 0, stream>>>(ihb, icb, meanb, ih_b, ic_b, hb, c, xfb);
    k_wb<<<dim3(12, G4), 256, 0, stream>>>(W_ih, W_hh, Wb);
    k_tr<<<dim3(16, 314), dim3(32, 8), 0, stream>>>(fc_W, fcWb, 512, VV);
    k_tr<<<dim3(16, 16),  dim3(32, 8), 0, stream>>>(U_a, Uab, 512, 512);
    k_tr<<<dim3(64, 16),  dim3(32, 8), 0, stream>>>(W_a, Wab, 2048, 512);
    k_waenc2<<<196, 512, 0, stream>>>(ebf, Wab, Waeb);
    k_pred<<<8, 256, 0, stream>>>(fcWb, fc_b, Uab, hb, dl, out, hU, 0, 1);

    for (int t = 0; t < MT; t++){
        k_energy<<<BB, 512, 0, stream>>>(Waeb, hU, hb, w_att, fb_W, fb_b,
                                         emb_table, captions, sidx, dl, xfb, attw, out, t);
        k_ctx<<<dim3(4, BB), 256, 0, stream>>>(ebf, attw, xfb);
        k_gates<<<dim3(32, 4), 256, 0, stream>>>(Wb, xfb, gacc);
        k_update<<<128, 256, 0, stream>>>(gacc, b_ih, b_hh, dl, hb, c, xfb, t);
        k_pred<<<165, 256, 0, stream>>>(fcWb, fc_b, Uab, hb, dl, out, hU, t, 0);
    }
}